// Round 1
// baseline (384.881 us; speedup 1.0000x reference)
//
#include <hip/hip_runtime.h>
#include <hip/hip_bf16.h>

// Problem constants (from reference)
#define NB 16
#define NVEC 2048
#define NDIM 32
#define NW 4
#define NHID 128
#define NCLASS 10

// Key identity: V_new = (h @ fw2 + 1*fb2^T) @ V = h @ (fw2 @ V) + 1*(fb2^T @ V)
// so we never materialize the [B,2048,2048] W tensor.
// ws layout (floats): X[NB*NVEC*NDIM] | VA[same] | VB[same] | U[NB*129*NDIM]
// U rows 0..127 = fw2@V, row 128 = fb2^T@V (the bias contribution).

__global__ __launch_bounds__(256) void k_embed(const int* __restrict__ data,
                                               const float* __restrict__ emb,
                                               float* __restrict__ X) {
    int gid = blockIdx.x * 256 + threadIdx.x;   // over NB*NVEC*NDIM = 1048576
    int row = gid >> 5;                          // b*NVEC + n
    int d = gid & 31;
    int tok = data[row];
    X[gid] = emb[tok * NDIM + d];
}

// U[b,k,d] = sum_m fw2[k,m] * V[b,m,d]   (k<128);  U[b,128,d] = sum_m fb2[m]*V[b,m,d]
// grid (NB, 17): each block handles 8 consecutive k for one b.
__global__ __launch_bounds__(256) void k_U(const float* __restrict__ V,
                                           const float* __restrict__ fw2,
                                           const float* __restrict__ fb2,
                                           float* __restrict__ U) {
    int b = blockIdx.x;
    int kg = blockIdx.y;                 // 0..16
    int tid = threadIdx.x;
    int d = tid & 31;
    int seg = tid >> 5;                  // 8 segments of 256 m's
    const float* Vb = V + b * (NVEC * NDIM);

    const float* wrow[8];
#pragma unroll
    for (int j = 0; j < 8; ++j) {
        int K = kg * 8 + j;
        wrow[j] = (K < NHID) ? (fw2 + K * NVEC) : fb2;  // K>128 rows computed but not stored
    }
    float acc[8];
#pragma unroll
    for (int j = 0; j < 8; ++j) acc[j] = 0.f;

    int m0 = seg * 256;
    for (int mi = 0; mi < 256; ++mi) {
        int m = m0 + mi;
        float v = Vb[m * NDIM + d];      // coalesced across d-lanes
#pragma unroll
        for (int j = 0; j < 8; ++j) acc[j] += wrow[j][m] * v;  // broadcast reads
    }

    __shared__ float red[8][8][33];      // [seg][j][d], padded
#pragma unroll
    for (int j = 0; j < 8; ++j) red[seg][j][d] = acc[j];
    __syncthreads();

    int jj = tid >> 5;                   // reuse 256 threads: one (j,d) output each
    float s = 0.f;
#pragma unroll
    for (int sg = 0; sg < 8; ++sg) s += red[sg][jj][d];
    int K = kg * 8 + jj;
    if (K <= NHID) U[(b * (NHID + 1) + K) * NDIM + d] = s;
}

// Fused: h = gelu(X @ fw1 + fb1) computed in LDS, then V_new = h @ U + U[128,:].
// grid (NB, NVEC/32): block handles 32 rows of one batch.
__global__ __launch_bounds__(256) void k_fused(const float* __restrict__ X,
                                               const float* __restrict__ fw1,
                                               const float* __restrict__ fb1,
                                               const float* __restrict__ U,
                                               float* __restrict__ Vout) {
    __shared__ float w1s[NDIM * NHID];        // 16 KB
    __shared__ float Us[(NHID + 1) * NDIM];   // 16.5 KB
    __shared__ float xs[32][NDIM];            // 4 KB
    __shared__ float hs[32][NHID];            // 16 KB
    int b = blockIdx.x;
    int n0 = blockIdx.y * 32;
    int tid = threadIdx.x;

    for (int i = tid; i < NDIM * NHID; i += 256) w1s[i] = fw1[i];
    for (int i = tid; i < (NHID + 1) * NDIM; i += 256) Us[i] = U[b * (NHID + 1) * NDIM + i];
    for (int i = tid; i < 32 * NDIM; i += 256)
        xs[i >> 5][i & 31] = X[(b * NVEC + n0) * NDIM + i];
    __syncthreads();

    // phase 1: h rows into LDS (exact GELU)
    int k = tid & 127;
    int rr = tid >> 7;                   // 0..1
    float bias = fb1[k];
    for (int it = 0; it < 16; ++it) {
        int r = 2 * it + rr;
        float acc = bias;
#pragma unroll
        for (int d = 0; d < NDIM; ++d) acc += xs[r][d] * w1s[d * NHID + k];
        hs[r][k] = 0.5f * acc * (1.0f + erff(acc * 0.70710678118654752f));
    }
    __syncthreads();

    // phase 2: V_new[r,d] = sum_k hs[r][k]*Us[k][d] + Us[128][d]
    int d = tid & 31;
    int nl = tid >> 5;
    for (int it = 0; it < 4; ++it) {
        int r = nl + 8 * it;
        float acc = Us[NHID * NDIM + d];
#pragma unroll 16
        for (int kk = 0; kk < NHID; ++kk) acc += hs[r][kk] * Us[kk * NDIM + d];
        Vout[(b * NVEC + n0 + r) * NDIM + d] = acc;
    }
}

__global__ void k_bias_out(const float* __restrict__ bf, float* __restrict__ out) {
    int t = threadIdx.x;
    if (t < NB * NCLASS) out[t] = bf[t % NCLASS];
}

// out[b,c] += sum_j V[b,j] * Wf[j,c];  grid (NB, 8), each block covers 8192 j's.
__global__ __launch_bounds__(256) void k_final(const float* __restrict__ V,
                                               const float* __restrict__ Wf,
                                               float* __restrict__ out) {
    int b = blockIdx.x, chunk = blockIdx.y;
    int tid = threadIdx.x;
    float acc[NCLASS];
#pragma unroll
    for (int c = 0; c < NCLASS; ++c) acc[c] = 0.f;
    const float* Vb = V + b * (NVEC * NDIM);
    int j0 = chunk * 8192;
    for (int j = j0 + tid; j < j0 + 8192; j += 256) {
        float v = Vb[j];
        const float* wr = Wf + j * NCLASS;
#pragma unroll
        for (int c = 0; c < NCLASS; ++c) acc[c] += v * wr[c];
    }
    __shared__ float red[256][NCLASS];   // 10 KB
#pragma unroll
    for (int c = 0; c < NCLASS; ++c) red[tid][c] = acc[c];
    __syncthreads();
    for (int off = 128; off >= 1; off >>= 1) {
        if (tid < off) {
#pragma unroll
            for (int c = 0; c < NCLASS; ++c) red[tid][c] += red[tid + off][c];
        }
        __syncthreads();
    }
    if (tid < NCLASS) atomicAdd(out + b * NCLASS + tid, red[0][tid]);
}

extern "C" void kernel_launch(void* const* d_in, const int* in_sizes, int n_in,
                              void* d_out, int out_size, void* d_ws, size_t ws_size,
                              hipStream_t stream) {
    const int*   data = (const int*)d_in[0];
    const float* emb  = (const float*)d_in[1];
    const float* fw1  = (const float*)d_in[2];
    const float* fb1  = (const float*)d_in[3];
    const float* fw2  = (const float*)d_in[4];
    const float* fb2  = (const float*)d_in[5];
    const float* Wf   = (const float*)d_in[6];
    const float* bf   = (const float*)d_in[7];
    float* out = (float*)d_out;

    float* X  = (float*)d_ws;                       // 1048576 floats
    float* VA = X  + NB * NVEC * NDIM;              // 1048576
    float* VB = VA + NB * NVEC * NDIM;              // 1048576
    float* U  = VB + NB * NVEC * NDIM;              // 16*129*32 = 66048

    k_embed<<<dim3((NB * NVEC * NDIM) / 256), 256, 0, stream>>>(data, emb, X);

    const float* Vcur = X;
    float* Vnext = VA;
    for (int i = NW - 1; i >= 0; --i) {
        k_U<<<dim3(NB, 17), 256, 0, stream>>>(Vcur, fw2 + i * NHID * NVEC,
                                              fb2 + i * NVEC, U);
        k_fused<<<dim3(NB, NVEC / 32), 256, 0, stream>>>(X, fw1 + i * NDIM * NHID,
                                                         fb1 + i * NHID, U, Vnext);
        Vcur = Vnext;
        Vnext = (Vnext == VA) ? VB : VA;
    }

    k_bias_out<<<1, 256, 0, stream>>>(bf, out);
    k_final<<<dim3(NB, 8), 256, 0, stream>>>(Vcur, Wf, out);
}

// Round 2
// 304.222 us; speedup vs baseline: 1.2651x; 1.2651x over previous
//
#include <hip/hip_runtime.h>
#include <hip/hip_bf16.h>

// Problem constants (from reference)
#define NB 16
#define NVEC 2048
#define NDIM 32
#define NW 4
#define NHID 128
#define NCLASS 10

// Key identity: V_new = (h @ fw2 + 1*fb2^T) @ V = h @ (fw2 @ V) + 1*(fb2^T @ V)
// U rows 0..127 = fw2@V, row 128 = fb2^T@V (bias contribution).
//
// ws layout (floats): X[NB*NVEC*NDIM] | VA[same] | VB[same] | U[NB*129*NDIM]
//                     | Upart[8 * NB * 136 * NDIM]

// ---------------------------------------------------------------------------
__global__ __launch_bounds__(256) void k_embed(const int* __restrict__ data,
                                               const float* __restrict__ emb,
                                               float* __restrict__ X) {
    int gid = blockIdx.x * 256 + threadIdx.x;   // over NB*NVEC*NDIM = 1048576
    int row = gid >> 5;                          // b*NVEC + n
    int d = gid & 31;
    int tok = data[row];
    X[gid] = emb[tok * NDIM + d];
}

// ---------------------------------------------------------------------------
// Split-K partial of U: grid (NB, 17, 8). Block (b,kg,ms) covers 8 k's and
// 256 m's. R0 had grid (16,17): 4.25 waves/CU, 10.6% occupancy, latency-bound
// at 53 us. Split-K x8 -> 34 waves/CU.
__global__ __launch_bounds__(256) void k_U(const float* __restrict__ V,
                                           const float* __restrict__ fw2,
                                           const float* __restrict__ fb2,
                                           float* __restrict__ Upart) {
    int b = blockIdx.x;
    int kg = blockIdx.y;                 // 0..16
    int ms = blockIdx.z;                 // 0..7
    int tid = threadIdx.x;
    int d = tid & 31;
    int seg = tid >> 5;                  // 8 segments of 32 m's
    const float* Vb = V + b * (NVEC * NDIM);

    const float* wrow[8];
#pragma unroll
    for (int j = 0; j < 8; ++j) {
        int K = kg * 8 + j;
        wrow[j] = (K < NHID) ? (fw2 + K * NVEC) : fb2;  // K>128 computed, ignored later
    }
    float acc[8];
#pragma unroll
    for (int j = 0; j < 8; ++j) acc[j] = 0.f;

    int m0 = ms * 256 + seg * 32;
#pragma unroll 4
    for (int mi = 0; mi < 32; ++mi) {
        int m = m0 + mi;
        float v = Vb[m * NDIM + d];      // coalesced across d-lanes
#pragma unroll
        for (int j = 0; j < 8; ++j) acc[j] += wrow[j][m] * v;  // half-wave-uniform reads
    }

    __shared__ float red[8][8][33];      // [seg][j][d], padded
#pragma unroll
    for (int j = 0; j < 8; ++j) red[seg][j][d] = acc[j];
    __syncthreads();

    int jj = tid >> 5;                   // one (j,d) output per thread
    float s = 0.f;
#pragma unroll
    for (int sg = 0; sg < 8; ++sg) s += red[sg][jj][d];
    // rows per (ms,b): 136 (17*8); k_Ured only reads k<129
    Upart[(((ms * NB + b) * 136) + kg * 8 + jj) * NDIM + d] = s;
}

// Reduce the 8 split-K partials: U[b,k,d] = sum_ms Upart[ms,b,k,d]
__global__ __launch_bounds__(256) void k_Ured(const float* __restrict__ Upart,
                                              float* __restrict__ U) {
    int gid = blockIdx.x * 256 + threadIdx.x;   // over NB*129*NDIM = 66048
    int d = gid & 31;
    int rest = gid >> 5;                        // b*129 + k
    int k = rest % 129;
    int b = rest / 129;
    float s = 0.f;
#pragma unroll
    for (int ms = 0; ms < 8; ++ms)
        s += Upart[(((ms * NB + b) * 136) + k) * NDIM + d];
    U[gid] = s;
}

// ---------------------------------------------------------------------------
// Fused: h = gelu(X @ fw1 + fb1) in LDS, then V_new = h @ U + U[128,:].
// grid (NB, NVEC/32). Phase 1: 2 rows per weight read (2 FMA chains);
// phase 2: 4 rows per Us read (4 FMA chains).
__global__ __launch_bounds__(256) void k_fused(const float* __restrict__ X,
                                               const float* __restrict__ fw1,
                                               const float* __restrict__ fb1,
                                               const float* __restrict__ U,
                                               float* __restrict__ Vout) {
    __shared__ float w1s[NDIM * NHID];        // 16 KB
    __shared__ float Us[(NHID + 1) * NDIM];   // 16.5 KB
    __shared__ float xs[32][NDIM];            // 4 KB
    __shared__ float hs[32][NHID];            // 16 KB
    int b = blockIdx.x;
    int n0 = blockIdx.y * 32;
    int tid = threadIdx.x;

    for (int i = tid; i < NDIM * NHID; i += 256) w1s[i] = fw1[i];
    for (int i = tid; i < (NHID + 1) * NDIM; i += 256) Us[i] = U[b * (NHID + 1) * NDIM + i];
    for (int i = tid; i < 32 * NDIM; i += 256)
        xs[i >> 5][i & 31] = X[(b * NVEC + n0) * NDIM + i];
    __syncthreads();

    // phase 1: h rows into LDS (exact GELU). 2 rows per thread per iter.
    int k = tid & 127;
    int rr = tid >> 7;                   // 0..1
    float bias = fb1[k];
#pragma unroll 2
    for (int it = 0; it < 8; ++it) {
        int r0 = 2 * it + rr;            // rows 0..15
        int r1 = r0 + 16;                // rows 16..31
        float a0 = bias, a1 = bias;
#pragma unroll
        for (int d = 0; d < NDIM; ++d) {
            float w = w1s[d * NHID + k];
            a0 += xs[r0][d] * w;
            a1 += xs[r1][d] * w;
        }
        hs[r0][k] = 0.5f * a0 * (1.0f + erff(a0 * 0.70710678118654752f));
        hs[r1][k] = 0.5f * a1 * (1.0f + erff(a1 * 0.70710678118654752f));
    }
    __syncthreads();

    // phase 2: V_new[r,d] = sum_k hs[r][k]*Us[k][d] + Us[128][d]; 4 rows/thread
    int d = tid & 31;
    int nl = tid >> 5;                   // 0..7
    float c = Us[NHID * NDIM + d];
    float a0 = c, a1 = c, a2 = c, a3 = c;
#pragma unroll 8
    for (int kk = 0; kk < NHID; ++kk) {
        float u = Us[kk * NDIM + d];
        a0 += hs[nl][kk] * u;
        a1 += hs[nl + 8][kk] * u;
        a2 += hs[nl + 16][kk] * u;
        a3 += hs[nl + 24][kk] * u;
    }
    float* o = Vout + (b * NVEC + n0) * NDIM + d;
    o[nl * NDIM] = a0;
    o[(nl + 8) * NDIM] = a1;
    o[(nl + 16) * NDIM] = a2;
    o[(nl + 24) * NDIM] = a3;
}

// ---------------------------------------------------------------------------
__global__ void k_bias_out(const float* __restrict__ bf, float* __restrict__ out) {
    int t = threadIdx.x;
    if (t < NB * NCLASS) out[t] = bf[t % NCLASS];
}

// out[b,c] += sum_j V[b,j] * Wf[j,c];  grid (NB, 8), each block covers 8192 j's.
__global__ __launch_bounds__(256) void k_final(const float* __restrict__ V,
                                               const float* __restrict__ Wf,
                                               float* __restrict__ out) {
    int b = blockIdx.x, chunk = blockIdx.y;
    int tid = threadIdx.x;
    float acc[NCLASS];
#pragma unroll
    for (int c = 0; c < NCLASS; ++c) acc[c] = 0.f;
    const float* Vb = V + b * (NVEC * NDIM);
    int j0 = chunk * 8192;
    for (int j = j0 + tid; j < j0 + 8192; j += 256) {
        float v = Vb[j];
        const float* wr = Wf + j * NCLASS;
#pragma unroll
        for (int c = 0; c < NCLASS; ++c) acc[c] += v * wr[c];
    }
    __shared__ float red[256][NCLASS];   // 10 KB
#pragma unroll
    for (int c = 0; c < NCLASS; ++c) red[tid][c] = acc[c];
    __syncthreads();
    for (int off = 128; off >= 1; off >>= 1) {
        if (tid < off) {
#pragma unroll
            for (int c = 0; c < NCLASS; ++c) red[tid][c] += red[tid + off][c];
        }
        __syncthreads();
    }
    if (tid < NCLASS) atomicAdd(out + b * NCLASS + tid, red[0][tid]);
}

// ---------------------------------------------------------------------------
extern "C" void kernel_launch(void* const* d_in, const int* in_sizes, int n_in,
                              void* d_out, int out_size, void* d_ws, size_t ws_size,
                              hipStream_t stream) {
    const int*   data = (const int*)d_in[0];
    const float* emb  = (const float*)d_in[1];
    const float* fw1  = (const float*)d_in[2];
    const float* fb1  = (const float*)d_in[3];
    const float* fw2  = (const float*)d_in[4];
    const float* fb2  = (const float*)d_in[5];
    const float* Wf   = (const float*)d_in[6];
    const float* bf   = (const float*)d_in[7];
    float* out = (float*)d_out;

    float* X     = (float*)d_ws;                    // 1048576 floats
    float* VA    = X  + NB * NVEC * NDIM;           // 1048576
    float* VB    = VA + NB * NVEC * NDIM;           // 1048576
    float* U     = VB + NB * NVEC * NDIM;           // 16*129*32 = 66048
    float* Upart = U + NB * 129 * NDIM;             // 8*16*136*32 = 557056

    k_embed<<<dim3((NB * NVEC * NDIM) / 256), 256, 0, stream>>>(data, emb, X);

    const float* Vcur = X;
    float* Vnext = VA;
    for (int i = NW - 1; i >= 0; --i) {
        k_U<<<dim3(NB, 17, 8), 256, 0, stream>>>(Vcur, fw2 + i * NHID * NVEC,
                                                 fb2 + i * NVEC, Upart);
        k_Ured<<<dim3(NB * 129 * NDIM / 256), 256, 0, stream>>>(Upart, U);
        k_fused<<<dim3(NB, NVEC / 32), 256, 0, stream>>>(X, fw1 + i * NDIM * NHID,
                                                         fb1 + i * NHID, U, Vnext);
        Vcur = Vnext;
        Vnext = (Vnext == VA) ? VB : VA;
    }

    k_bias_out<<<1, 256, 0, stream>>>(bf, out);
    k_final<<<dim3(NB, 8), 256, 0, stream>>>(Vcur, Wf, out);
}

// Round 3
// 235.140 us; speedup vs baseline: 1.6368x; 1.2938x over previous
//
#include <hip/hip_runtime.h>
#include <hip/hip_bf16.h>

#define NB 16
#define NVEC 2048
#define NDIM 32
#define NW 4
#define NHID 128
#define NCLASS 10
#define MS 16              // m-splits for k_U
#define USIZE (129 * 32)   // 4128 floats: U rows 0..127 = fw2@V, row 128 = fb2^T@V

__device__ __forceinline__ float gelu_exact(float x) {
    return 0.5f * x * (1.0f + erff(x * 0.70710678118654752f));
}

// ---------------------------------------------------------------------------
__global__ __launch_bounds__(256) void k_embed(const int* __restrict__ data,
                                               const float* __restrict__ emb,
                                               float* __restrict__ X) {
    int gid = blockIdx.x * 256 + threadIdx.x;   // NB*NVEC*NDIM = 1048576
    int row = gid >> 5;
    int d = gid & 31;
    X[gid] = emb[data[row] * NDIM + d];
}

// ---------------------------------------------------------------------------
// All-layer h precompute: h[l,b,n,k] = gelu(X[b,n,:] @ fw1[l][:,k] + fb1[l][k])
// grid (NVEC/64, NB, NW). Register tile: 4 rows x 8 k per thread.
__global__ __launch_bounds__(256) void k_H(const float* __restrict__ X,
                                           const float* __restrict__ fw1,
                                           const float* __restrict__ fb1,
                                           float* __restrict__ H) {
    __shared__ float w1s[NDIM * NHID];   // [d][k] native layout, 16 KB
    __shared__ float xt[NDIM][68];       // [d][r] transposed, pad 4 (16B row align)
    int n0 = blockIdx.x * 64;
    int b = blockIdx.y;
    int l = blockIdx.z;
    int tid = threadIdx.x;

    const float* w1 = fw1 + l * NDIM * NHID;
    for (int i = tid; i < NDIM * NHID; i += 256) w1s[i] = w1[i];
    const float* Xb = X + (b * NVEC + n0) * NDIM;
#pragma unroll
    for (int j = 0; j < 8; ++j) {
        int i = tid + j * 256;           // 2048 elements
        xt[i & 31][i >> 5] = Xb[i];
    }
    __syncthreads();

    int kg = tid & 15, rg = tid >> 4;    // 16 k-groups x 16 r-groups
    int k0 = kg * 8, r0 = rg * 4;
    const float* fb = fb1 + l * NHID;
    float acc[4][8];
#pragma unroll
    for (int j = 0; j < 8; ++j) {
        float bv = fb[k0 + j];
#pragma unroll
        for (int r = 0; r < 4; ++r) acc[r][j] = bv;
    }

#pragma unroll 8
    for (int d = 0; d < NDIM; ++d) {
        float4 xv = *(const float4*)&xt[d][r0];
        float4 wa = *(const float4*)&w1s[d * NHID + k0];
        float4 wb = *(const float4*)&w1s[d * NHID + k0 + 4];
        float xr[4] = {xv.x, xv.y, xv.z, xv.w};
        float wk[8] = {wa.x, wa.y, wa.z, wa.w, wb.x, wb.y, wb.z, wb.w};
#pragma unroll
        for (int r = 0; r < 4; ++r)
#pragma unroll
            for (int j = 0; j < 8; ++j) acc[r][j] += xr[r] * wk[j];
    }

    float* hb = H + (((size_t)l * NB + b) * NVEC + n0) * NHID;
#pragma unroll
    for (int r = 0; r < 4; ++r) {
        float4 o0, o1;
        o0.x = gelu_exact(acc[r][0]); o0.y = gelu_exact(acc[r][1]);
        o0.z = gelu_exact(acc[r][2]); o0.w = gelu_exact(acc[r][3]);
        o1.x = gelu_exact(acc[r][4]); o1.y = gelu_exact(acc[r][5]);
        o1.z = gelu_exact(acc[r][6]); o1.w = gelu_exact(acc[r][7]);
        *(float4*)&hb[(r0 + r) * NHID + k0] = o0;
        *(float4*)&hb[(r0 + r) * NHID + k0 + 4] = o1;
    }
}

// ---------------------------------------------------------------------------
// Split-m partial U: grid (MS, NB). Block handles 128 m's for one b.
// Thread tile: 2 k (k, k+64) x 8 d. LDS-staged V-tile + fw2 sub-tiles.
__global__ __launch_bounds__(256) void k_U(const float* __restrict__ V,
                                           const float* __restrict__ fw2,
                                           const float* __restrict__ fb2,
                                           float* __restrict__ Upart) {
    __shared__ float Vs[128 * 32];       // [mm][d], 16 KB
    __shared__ float fw2s[128][33];      // [k][mm] pad 1 -> conflict-free k-lanes
    __shared__ float cred[4][33];
    int ms = blockIdx.x, b = blockIdx.y;
    int tid = threadIdx.x;
    int m0 = ms * 128;

    const float* Vb = V + (b * NVEC + m0) * NDIM;
#pragma unroll
    for (int j = 0; j < 4; ++j) {
        int i4 = tid + j * 256;          // 1024 float4s
        ((float4*)Vs)[i4] = ((const float4*)Vb)[i4];
    }

    int k1 = tid & 63, k2 = k1 + 64, dg = tid >> 6;
    int d0 = dg * 8;
    float acc1[8], acc2[8];
#pragma unroll
    for (int j = 0; j < 8; ++j) { acc1[j] = 0.f; acc2[j] = 0.f; }

    for (int s = 0; s < 4; ++s) {
        __syncthreads();                 // covers Vs staging (s=0) + prior tile reads
        int moff = m0 + s * 32;
#pragma unroll
        for (int j = 0; j < 16; ++j) {
            int i = tid + j * 256;       // 4096 elements
            int kk = i >> 5, mm = i & 31;
            fw2s[kk][mm] = fw2[kk * NVEC + moff + mm];
        }
        __syncthreads();
#pragma unroll 8
        for (int mm = 0; mm < 32; ++mm) {
            float w1v = fw2s[k1][mm];
            float w2v = fw2s[k2][mm];
            const float* vrow = &Vs[(s * 32 + mm) * 32 + d0];
            float4 va = *(const float4*)vrow;
            float4 vb4 = *(const float4*)(vrow + 4);
            float vv[8] = {va.x, va.y, va.z, va.w, vb4.x, vb4.y, vb4.z, vb4.w};
#pragma unroll
            for (int j = 0; j < 8; ++j) {
                acc1[j] += w1v * vv[j];
                acc2[j] += w2v * vv[j];
            }
        }
    }

    float* Up = Upart + ((size_t)ms * NB + b) * USIZE;
    *(float4*)&Up[k1 * 32 + d0]     = make_float4(acc1[0], acc1[1], acc1[2], acc1[3]);
    *(float4*)&Up[k1 * 32 + d0 + 4] = make_float4(acc1[4], acc1[5], acc1[6], acc1[7]);
    *(float4*)&Up[k2 * 32 + d0]     = make_float4(acc2[0], acc2[1], acc2[2], acc2[3]);
    *(float4*)&Up[k2 * 32 + d0 + 4] = make_float4(acc2[4], acc2[5], acc2[6], acc2[7]);

    // bias row: c[d] = sum_m fb2[m] * V[b,m,d]
    if (tid < 128) {
        int d = tid & 31, seg = tid >> 5;
        float ca = 0.f;
#pragma unroll 8
        for (int mm = seg * 32; mm < seg * 32 + 32; ++mm)
            ca += fb2[m0 + mm] * Vs[mm * 32 + d];
        cred[seg][d] = ca;
    }
    __syncthreads();
    if (tid < 32)
        Up[128 * 32 + tid] = cred[0][tid] + cred[1][tid] + cred[2][tid] + cred[3][tid];
}

// ---------------------------------------------------------------------------
// Apply: V_new[b,n,d] = sum_k h[b,n,k] * U[b,k,d] + U[b,128,d]
// grid (NVEC/64, NB). Fuses the MS-partial reduction of U into staging.
// Thread tile: 2 rows x 4 d over K=128.
__global__ __launch_bounds__(256) void k_apply(const float* __restrict__ Hl,
                                               const float* __restrict__ Upart,
                                               float* __restrict__ Vout) {
    __shared__ float UsF[USIZE];         // 16.5 KB
    __shared__ float hs[64][132];        // 33.8 KB, pad 4 (16B align, 2-way banks)
    int n0 = blockIdx.x * 64;
    int b = blockIdx.y;
    int tid = threadIdx.x;

    for (int i = tid; i < USIZE; i += 256) {
        float s = 0.f;
#pragma unroll
        for (int msx = 0; msx < MS; ++msx)
            s += Upart[((size_t)msx * NB + b) * USIZE + i];
        UsF[i] = s;
    }
    const float* hb = Hl + ((size_t)b * NVEC + n0) * NHID;
#pragma unroll
    for (int j = 0; j < 8; ++j) {
        int i4 = tid + j * 256;          // 2048 float4s
        float4 v = ((const float4*)hb)[i4];
        int row = i4 >> 5, c4 = (i4 & 31) * 4;
        *(float4*)&hs[row][c4] = v;
    }
    __syncthreads();

    int dg = tid & 7, rg = tid >> 3;     // 8 d-groups x 32 row-groups
    int d0 = dg * 4, r0 = rg * 2;
    float4 cb = *(const float4*)&UsF[128 * 32 + d0];
    float4 a0 = cb, a1 = cb;
#pragma unroll 8
    for (int k = 0; k < NHID; k += 4) {
        float4 h0 = *(const float4*)&hs[r0][k];
        float4 h1 = *(const float4*)&hs[r0 + 1][k];
        float4 u0 = *(const float4*)&UsF[(k + 0) * 32 + d0];
        float4 u1 = *(const float4*)&UsF[(k + 1) * 32 + d0];
        float4 u2 = *(const float4*)&UsF[(k + 2) * 32 + d0];
        float4 u3 = *(const float4*)&UsF[(k + 3) * 32 + d0];
        a0.x += h0.x * u0.x + h0.y * u1.x + h0.z * u2.x + h0.w * u3.x;
        a0.y += h0.x * u0.y + h0.y * u1.y + h0.z * u2.y + h0.w * u3.y;
        a0.z += h0.x * u0.z + h0.y * u1.z + h0.z * u2.z + h0.w * u3.z;
        a0.w += h0.x * u0.w + h0.y * u1.w + h0.z * u2.w + h0.w * u3.w;
        a1.x += h1.x * u0.x + h1.y * u1.x + h1.z * u2.x + h1.w * u3.x;
        a1.y += h1.x * u0.y + h1.y * u1.y + h1.z * u2.y + h1.w * u3.y;
        a1.z += h1.x * u0.z + h1.y * u1.z + h1.z * u2.z + h1.w * u3.z;
        a1.w += h1.x * u0.w + h1.y * u1.w + h1.z * u2.w + h1.w * u3.w;
    }
    float* vo = Vout + ((size_t)b * NVEC + n0 + r0) * NDIM + d0;
    *(float4*)vo = a0;
    *(float4*)(vo + NDIM) = a1;
}

// ---------------------------------------------------------------------------
__global__ void k_bias_out(const float* __restrict__ bf, float* __restrict__ out) {
    int t = threadIdx.x;
    if (t < NB * NCLASS) out[t] = bf[t % NCLASS];
}

// out[b,c] += sum_j V[b,j] * Wf[j,c];  grid (NB, 32), 2048 j's per block.
__global__ __launch_bounds__(256) void k_final(const float* __restrict__ V,
                                               const float* __restrict__ Wf,
                                               float* __restrict__ out) {
    int b = blockIdx.x, chunk = blockIdx.y;
    int tid = threadIdx.x;
    float acc[NCLASS];
#pragma unroll
    for (int c = 0; c < NCLASS; ++c) acc[c] = 0.f;
    const float* Vb = V + b * (NVEC * NDIM);
    int j0 = chunk * 2048;
    for (int j = j0 + tid; j < j0 + 2048; j += 256) {
        float v = Vb[j];
        const float* wr = Wf + (size_t)j * NCLASS;
#pragma unroll
        for (int c = 0; c < NCLASS; ++c) acc[c] += v * wr[c];
    }
    __shared__ float red[256][NCLASS];
#pragma unroll
    for (int c = 0; c < NCLASS; ++c) red[tid][c] = acc[c];
    __syncthreads();
    for (int off = 128; off >= 1; off >>= 1) {
        if (tid < off) {
#pragma unroll
            for (int c = 0; c < NCLASS; ++c) red[tid][c] += red[tid + off][c];
        }
        __syncthreads();
    }
    if (tid < NCLASS) atomicAdd(out + b * NCLASS + tid, red[0][tid]);
}

// ---------------------------------------------------------------------------
extern "C" void kernel_launch(void* const* d_in, const int* in_sizes, int n_in,
                              void* d_out, int out_size, void* d_ws, size_t ws_size,
                              hipStream_t stream) {
    const int*   data = (const int*)d_in[0];
    const float* emb  = (const float*)d_in[1];
    const float* fw1  = (const float*)d_in[2];
    const float* fb1  = (const float*)d_in[3];
    const float* fw2  = (const float*)d_in[4];
    const float* fb2  = (const float*)d_in[5];
    const float* Wf   = (const float*)d_in[6];
    const float* bf   = (const float*)d_in[7];
    float* out = (float*)d_out;

    float* X     = (float*)d_ws;                        // 1048576
    float* VA    = X + NB * NVEC * NDIM;                // 1048576
    float* VB    = VA + NB * NVEC * NDIM;               // 1048576
    float* H     = VB + NB * NVEC * NDIM;               // 4*16*2048*128 = 16777216 (64 MB)
    float* Upart = H + (size_t)NW * NB * NVEC * NHID;   // 16*16*4128 = 1056768

    k_embed<<<dim3((NB * NVEC * NDIM) / 256), 256, 0, stream>>>(data, emb, X);
    k_H<<<dim3(NVEC / 64, NB, NW), 256, 0, stream>>>(X, fw1, fb1, H);

    const float* Vcur = X;
    float* Vnext = VA;
    for (int i = NW - 1; i >= 0; --i) {
        k_U<<<dim3(MS, NB), 256, 0, stream>>>(Vcur, fw2 + (size_t)i * NHID * NVEC,
                                              fb2 + (size_t)i * NVEC, Upart);
        k_apply<<<dim3(NVEC / 64, NB), 256, 0, stream>>>(
            H + (size_t)i * NB * NVEC * NHID, Upart, Vnext);
        Vcur = Vnext;
        Vnext = (Vnext == VA) ? VB : VA;
    }

    k_bias_out<<<1, 256, 0, stream>>>(bf, out);
    k_final<<<dim3(NB, 32), 256, 0, stream>>>(Vcur, Wf, out);
}